// Round 13
// baseline (1248.075 us; speedup 1.0000x reference)
//
#include <hip/hip_runtime.h>

#define Bn 32
#define Tn 512
#define Dn 512
#define Vn 512

typedef float f4 __attribute__((ext_vector_type(4)));
typedef int i8v __attribute__((ext_vector_type(8)));
typedef _Float16 h8f __attribute__((ext_vector_type(8)));

__device__ __forceinline__ float max8lds(const float* p) {
  float4 a = *(const float4*)p;
  float4 b = *(const float4*)(p + 4);
  return fmaxf(fmaxf(fmaxf(a.x, a.y), fmaxf(a.z, a.w)),
               fmaxf(fmaxf(b.x, b.y), fmaxf(b.z, b.w)));
}

// 64-lane max via DPP (row_shr 1/2/4/8 + bcast15/31), result broadcast via readlane
__device__ __forceinline__ float dpp64max(float x) {
  int t;
  t = __builtin_amdgcn_update_dpp(__float_as_int(x), __float_as_int(x), 0x111, 0xF, 0xF, false);
  x = fmaxf(x, __int_as_float(t));
  t = __builtin_amdgcn_update_dpp(__float_as_int(x), __float_as_int(x), 0x112, 0xF, 0xF, false);
  x = fmaxf(x, __int_as_float(t));
  t = __builtin_amdgcn_update_dpp(__float_as_int(x), __float_as_int(x), 0x114, 0xF, 0xF, false);
  x = fmaxf(x, __int_as_float(t));
  t = __builtin_amdgcn_update_dpp(__float_as_int(x), __float_as_int(x), 0x118, 0xF, 0xF, false);
  x = fmaxf(x, __int_as_float(t));
  t = __builtin_amdgcn_update_dpp(__float_as_int(x), __float_as_int(x), 0x142, 0xF, 0xF, false);
  x = fmaxf(x, __int_as_float(t));
  t = __builtin_amdgcn_update_dpp(__float_as_int(x), __float_as_int(x), 0x143, 0xF, 0xF, false);
  x = fmaxf(x, __int_as_float(t));
  return __int_as_float(__builtin_amdgcn_readlane(__float_as_int(x), 63));
}

// raw barrier: LDS-visibility only (no vmcnt drain -> global ops float across steps)
__device__ __forceinline__ void bar_lgkm() {
  asm volatile("s_waitcnt lgkmcnt(0)" ::: "memory");
  __builtin_amdgcn_s_barrier();
}

// ---- f32 -> OCP e4m3fn, round-to-nearest-even (x >= 0 assumed) ----
__device__ __forceinline__ unsigned int f32_to_e4m3(float x) {
  x = fminf(x, 448.0f);
  unsigned int bits = __float_as_uint(x);
  int e = (int)((bits >> 23) & 0xFF) - 127;
  if (e < -6) {
    return (unsigned int)__float2int_rn(x * 512.0f);
  }
  unsigned int man = bits & 0x7FFFFF;
  int te = e + 7;
  unsigned int r = man >> 20;
  unsigned int rem = man & 0xFFFFF;
  if (rem > 0x80000u || (rem == 0x80000u && (r & 1u))) r++;
  if (r == 8u) { r = 0u; te++; }
  if (te > 15) { te = 15; r = 6u; }
  unsigned int byte = ((unsigned int)te << 3) | r;
  if (byte > 0x7Eu) byte = 0x7Eu;
  return byte;
}

// ---- pruning radius: max over columns v of (max_u T[u][v] - min_u T[u][v]) ----
__global__ __launch_bounds__(512) void crf_minmax(const float* __restrict__ trans,
                                                  unsigned int* __restrict__ Rout) {
  __shared__ float smn[8][64], smx[8][64];
  const int c = threadIdx.x & 63;
  const int seg = threadIdx.x >> 6;
  const int col = (int)blockIdx.x * 64 + c;
  float mn = 3e38f, mx = -3e38f;
#pragma unroll 4
  for (int u = seg * 64; u < seg * 64 + 64; ++u) {
    float t = trans[(size_t)u * Vn + col];
    mn = fminf(mn, t); mx = fmaxf(mx, t);
  }
  smn[seg][c] = mn; smx[seg][c] = mx;
  __syncthreads();
  if (seg == 0) {
#pragma unroll
    for (int i = 1; i < 8; ++i) { mn = fminf(mn, smn[i][c]); mx = fmaxf(mx, smx[i][c]); }
    float r = dpp64max(mx - mn);  // r >= 0
    if (c == 0) atomicMax((int*)Rout, __float_as_int(r));
  }
}

// ---- E8: exp(trans) as fp8 e4m3 MFMA A-fragments for 16x16x128 ----
__global__ __launch_bounds__(256) void crf_build_E8(const float* __restrict__ trans,
                                                    unsigned char* __restrict__ E8) {
  const int fid = (int)blockIdx.x;       // 0..127 = vt*4 + kc
  const int vt = fid >> 2, kc = fid & 3;
  const int t = threadIdx.x;             // 8 bytes per thread
  const int lane = t >> 2;
  const int j0 = (t & 3) * 8;
  const int v = vt * 16 + (lane & 15);
  const int ubase = kc * 128 + (lane >> 4) * 32 + j0;
  unsigned long long pack = 0;
#pragma unroll
  for (int s = 0; s < 8; ++s) {
    float e = __expf(trans[(size_t)(ubase + s) * Vn + v]);
    pack |= (unsigned long long)f32_to_e4m3(e) << (8 * s);
  }
  *(unsigned long long*)(E8 + (size_t)fid * 2048 + lane * 32 + j0) = pack;
}

// ---- emissions via split-f16 MFMA (f32-accurate): BM=64, BN=512, BK=32 ----
__global__ __launch_bounds__(256) void crf_gemm(const float* __restrict__ X,
                                                const float* __restrict__ Wt,
                                                float* __restrict__ C) {
  __shared__ h8f XfH[4][64], XfL[4][64];    // 8 KB
  __shared__ h8f WfH[32][64], WfL[32][64];  // 64 KB
  const int tid = threadIdx.x;
  const int m0 = (int)blockIdx.x * 64;
  const int wv = tid >> 6, lane = tid & 63;
  const int g = lane >> 4, cc = lane & 15;
  const int srow = tid >> 2;                // 0..63
  const int sc0 = (tid & 3) * 8;            // k-chunk 0/8/16/24
  const int p = (tid & 3) * 16 + ((tid >> 2) & 15);  // fragment slot
  f4 acc[32];
#pragma unroll
  for (int i = 0; i < 32; ++i) acc[i] = (f4)(0.f);

  for (int k0 = 0; k0 < Dn; k0 += 32) {
    __syncthreads();
    {
      const float* xp = X + (size_t)(m0 + srow) * Dn + k0 + sc0;
      float4 xa = *(const float4*)xp;
      float4 xb = *(const float4*)(xp + 4);
      float xs[8] = {xa.x, xa.y, xa.z, xa.w, xb.x, xb.y, xb.z, xb.w};
      _Float16 hh[8], ll[8];
#pragma unroll
      for (int i = 0; i < 8; ++i) {
        hh[i] = (_Float16)xs[i];
        ll[i] = (_Float16)(xs[i] - (float)hh[i]);
      }
      XfH[tid >> 6][p] = *(h8f*)hh;
      XfL[tid >> 6][p] = *(h8f*)ll;
#pragma unroll
      for (int i = 0; i < 8; ++i) {
        int r = i * 64 + srow;
        const float* wp = Wt + (size_t)r * Dn + k0 + sc0;
        float4 wa = *(const float4*)wp;
        float4 wb = *(const float4*)(wp + 4);
        float wsv[8] = {wa.x, wa.y, wa.z, wa.w, wb.x, wb.y, wb.z, wb.w};
        _Float16 wh[8], wl[8];
#pragma unroll
        for (int q = 0; q < 8; ++q) {
          wh[q] = (_Float16)wsv[q];
          wl[q] = (_Float16)(wsv[q] - (float)wh[q]);
        }
        WfH[i * 4 + (tid >> 6)][p] = *(h8f*)wh;
        WfL[i * 4 + (tid >> 6)][p] = *(h8f*)wl;
      }
    }
    __syncthreads();
    h8f aH = XfH[wv][lane];
    h8f aL = XfL[wv][lane];
#pragma unroll
    for (int nt = 0; nt < 32; ++nt) {
      h8f bH = WfH[nt][lane];
      h8f bL = WfL[nt][lane];
      acc[nt] = __builtin_amdgcn_mfma_f32_16x16x32_f16(aH, bH, acc[nt], 0, 0, 0);
      acc[nt] = __builtin_amdgcn_mfma_f32_16x16x32_f16(aH, bL, acc[nt], 0, 0, 0);
      acc[nt] = __builtin_amdgcn_mfma_f32_16x16x32_f16(aL, bH, acc[nt], 0, 0, 0);
      acc[nt] = __builtin_amdgcn_mfma_f32_16x16x32_f16(aL, bL, acc[nt], 0, 0, 0);
    }
  }
#pragma unroll
  for (int nt = 0; nt < 32; ++nt)
#pragma unroll
    for (int r = 0; r < 4; ++r)
      C[(size_t)(m0 + wv * 16 + 4 * g + r) * Vn + nt * 16 + cc] = acc[nt][r];
}

// ---- shared-memory union: forward vs viterbi roles ----
union SM {
  struct {
    __align__(16) unsigned char ph[2][Vn];   // parity-double-buffered fp8 p
    __align__(16) float wred[2][8];          // parity-double-buffered wave maxes
    __align__(16) float wred2[8];
    unsigned char padsh[Tn];
  } f;
  struct {
    __align__(16) float va2[2][Vn];
    __align__(16) unsigned short bpbuf[32][Vn];
    unsigned short tokens[Tn];
    __align__(16) float wvals[8];
    int widxs[8];
    unsigned char padsh[Tn];
    int lastS;
  } v;
};

// ---- fused scan + probes:
// blocks 0..31 forward (real), 32..63 viterbi (real),
// 64..127 probeV-skel x2 steps, 128..191 probeF-1bar x2 steps ----
__global__ __launch_bounds__(512, 2) void crf_scan(
    const float* __restrict__ emis, const float* __restrict__ trans,
    const unsigned char* __restrict__ E8, const float* __restrict__ Rp,
    const int* __restrict__ tgt, const unsigned char* __restrict__ pad,
    unsigned short* __restrict__ bps, float* __restrict__ out_ll,
    float* __restrict__ out_tok, float* __restrict__ sink) {
  __shared__ SM sm;

  const int tid = threadIdx.x;
  const int b = blockIdx.x & 31;
  const int role = blockIdx.x >> 5;
  const float* eb = emis + (size_t)b * Tn * Vn;
  const int w = tid >> 6;
  const int lane = tid & 63;

  if (role == 0) {
    // ========== FORWARD (real, r12-identical: 2-barrier exact-m fp8) ==========
    const int g = lane >> 4, c = lane & 15;
    const int t2sel = c >> 2, r2sel = c & 3;
    const int sidx = ((16 * ((lane >> 2) & 3)) + 4 * (lane >> 4) + (lane & 3)) << 2;
    i8v EA[4][4];
    {
      const i8v* E8v = (const i8v*)E8;
#pragma unroll
      for (int vt2 = 0; vt2 < 4; ++vt2)
#pragma unroll
        for (int kc = 0; kc < 4; ++kc)
          EA[vt2][kc] = E8v[((4 * w + vt2) * 4 + kc) * 64 + lane];
    }
    sm.f.padsh[tid] = pad[b * Tn + tid];
    float alphaR = eb[tid];
    float ecur = eb[Vn + tid];
    {
      float r = dpp64max(alphaR);
      if (lane == 0) sm.f.wred[0][w] = r;
    }
    bar_lgkm();
    float m = max8lds(sm.f.wred[0]);

    for (int t = 1; t < Tn; ++t) {
      float p = __expf(alphaR - m);
      sm.f.ph[0][tid] = (unsigned char)f32_to_e4m3(p);
      bar_lgkm();  // A: ph visible
      float enext = (t + 1 < Tn) ? eb[(size_t)(t + 1) * Vn + tid] : 0.f;
      const uint4* phq = (const uint4*)sm.f.ph[0];
      i8v B4[4];
#pragma unroll
      for (int kc = 0; kc < 4; ++kc) {
        union { uint4 u[2]; i8v v; } bu;
        bu.u[0] = phq[kc * 8 + g * 2];
        bu.u[1] = phq[kc * 8 + g * 2 + 1];
        B4[kc] = bu.v;
      }
      f4 acc0 = (f4)(0.f), acc1 = (f4)(0.f), acc2 = (f4)(0.f), acc3 = (f4)(0.f);
#pragma unroll
      for (int kc = 0; kc < 4; ++kc) {
        acc0 = __builtin_amdgcn_mfma_scale_f32_16x16x128_f8f6f4(
            EA[0][kc], B4[kc], acc0, 0, 0, 0, 0x7F7F7F7F, 0, 0x7F7F7F7F);
        acc1 = __builtin_amdgcn_mfma_scale_f32_16x16x128_f8f6f4(
            EA[1][kc], B4[kc], acc1, 0, 0, 0, 0x7F7F7F7F, 0, 0x7F7F7F7F);
        acc2 = __builtin_amdgcn_mfma_scale_f32_16x16x128_f8f6f4(
            EA[2][kc], B4[kc], acc2, 0, 0, 0, 0x7F7F7F7F, 0, 0x7F7F7F7F);
        acc3 = __builtin_amdgcn_mfma_scale_f32_16x16x128_f8f6f4(
            EA[3][kc], B4[kc], acc3, 0, 0, 0, 0x7F7F7F7F, 0, 0x7F7F7F7F);
      }
      f4 at = (t2sel == 0) ? acc0 : (t2sel == 1) ? acc1 : (t2sel == 2) ? acc2 : acc3;
      float lo = (r2sel & 1) ? at[1] : at[0];
      float hi = (r2sel & 1) ? at[3] : at[2];
      float tot = (r2sel & 2) ? hi : lo;
      float tv = __int_as_float(__builtin_amdgcn_ds_bpermute(sidx, __float_as_int(tot)));
      float nv = m + __logf(tv) + ecur;
      if (sm.f.padsh[t]) nv = alphaR;
      alphaR = nv; ecur = enext;
      float rmx = dpp64max(nv);
      if (lane == 0) sm.f.wred[0][w] = rmx;
      bar_lgkm();  // B: wred visible
      m = max8lds(sm.f.wred[0]);
    }

    __syncthreads();
    float ex = __expf(alphaR - m);
#pragma unroll
    for (int off = 1; off < 64; off <<= 1) ex += __shfl_xor(ex, off);
    if (lane == 0) sm.f.wred[0][w] = ex;
    float sc;
    {
      int t = tid;
      int tg = tgt[b * Tn + t];
      float mt = sm.f.padsh[t] ? 0.f : 1.f;
      sc = eb[(size_t)t * Vn + tg] * mt;
      if (t < Tn - 1) {
        int tg1 = tgt[b * Tn + t + 1];
        float mt1 = sm.f.padsh[t + 1] ? 0.f : 1.f;
        sc += trans[(size_t)tg * Vn + tg1] * mt * mt1;
      }
    }
#pragma unroll
    for (int off = 1; off < 64; off <<= 1) sc += __shfl_xor(sc, off);
    if (lane == 0) sm.f.wred2[w] = sc;
    __syncthreads();
    if (tid == 0) {
      float s = 0.f, gg = 0.f;
      for (int i = 0; i < 8; ++i) { s += sm.f.wred[0][i]; gg += sm.f.wred2[i]; }
      out_ll[b] = gg - (m + __logf(s));
    }
  } else if (role == 1) {
    // ========== VITERBI (real, r12-identical) ==========
    float R = __int_as_float(((const int*)Rp)[0]) * 1.000001f + 1e-4f;
    sm.v.padsh[tid] = pad[b * Tn + tid];
    float vaR = eb[tid];
    sm.v.va2[0][tid] = vaR;
    float ecur = eb[Vn + tid];
    bar_lgkm();

    for (int t = 1; t < Tn; ++t) {
      const int cur = t & 1, prev = cur ^ 1;
      const float* va2p = sm.v.va2[prev];
      const float4* vap4 = (const float4*)va2p;
      float4 q0 = vap4[lane * 2];
      float4 q1 = vap4[lane * 2 + 1];
      float mx8 = fmaxf(fmaxf(fmaxf(q0.x, q0.y), fmaxf(q0.z, q0.w)),
                        fmaxf(fmaxf(q1.x, q1.y), fmaxf(q1.z, q1.w)));
      float gmax = dpp64max(mx8);
      float thr = gmax - R;
      unsigned long long bm[8];
      bm[0] = __ballot(q0.x >= thr);
      bm[1] = __ballot(q0.y >= thr);
      bm[2] = __ballot(q0.z >= thr);
      bm[3] = __ballot(q0.w >= thr);
      bm[4] = __ballot(q1.x >= thr);
      bm[5] = __ballot(q1.y >= thr);
      bm[6] = __ballot(q1.z >= thr);
      bm[7] = __ballot(q1.w >= thr);
      unsigned long long any = bm[0] | bm[1] | bm[2] | bm[3] |
                               bm[4] | bm[5] | bm[6] | bm[7];
      float enext = (t + 1 < Tn) ? eb[(size_t)(t + 1) * Vn + tid] : 0.f;
      float best = -3e38f; int arg = 0;
      while (any) {
        int l = __ffsll(any) - 1; any &= any - 1;
#pragma unroll
        for (int j = 0; j < 8; ++j) {
          if ((bm[j] >> l) & 1) {
            int u = 8 * l + j;
            float cnd = va2p[u] + trans[(size_t)u * Vn + tid];
            if (cnd > best) { best = cnd; arg = u; }
          }
        }
      }
      float nv = best + ecur; int bp = arg;
      if (sm.v.padsh[t]) { nv = vaR; bp = tid; }
      bps[((size_t)(t - 1) * Bn + b) * Vn + tid] = (unsigned short)bp;
      sm.v.va2[cur][tid] = nv;
      vaR = nv; ecur = enext;
      bar_lgkm();
    }

    asm volatile("s_waitcnt vmcnt(0)" ::: "memory");
    __syncthreads();

    {
      float val = vaR;
      int idx = tid;
#pragma unroll
      for (int off = 1; off < 64; off <<= 1) {
        float ov = __shfl_xor(val, off);
        int oi = __shfl_xor(idx, off);
        if (ov > val || (ov == val && oi < idx)) { val = ov; idx = oi; }
      }
      if (lane == 0) { sm.v.wvals[w] = val; sm.v.widxs[w] = idx; }
    }
    __syncthreads();
    if (tid == 0) {
      float bv = sm.v.wvals[0]; int bi = sm.v.widxs[0];
      for (int i = 1; i < 8; ++i)
        if (sm.v.wvals[i] > bv || (sm.v.wvals[i] == bv && sm.v.widxs[i] < bi)) {
          bv = sm.v.wvals[i]; bi = sm.v.widxs[i];
        }
      sm.v.lastS = bi;
    }
    __syncthreads();
    int tok = sm.v.lastS;

    for (int cch = 15; cch >= 0; --cch) {
      int rhi = cch * 32 + 31; if (rhi > 510) rhi = 510;
      int srow = tid >> 4, part = tid & 15;
      int row = cch * 32 + srow;
      if (row <= 510) {
        const uint4* src = (const uint4*)(bps + ((size_t)row * Bn + b) * Vn);
        uint4* dst = (uint4*)&sm.v.bpbuf[srow][0];
#pragma unroll
        for (int qq = 0; qq < 4; ++qq) dst[part * 4 + qq] = src[part * 4 + qq];
      }
      __syncthreads();
      if (tid == 0) {
        int tk = tok;
        for (int rr = rhi; rr >= cch * 32; --rr) {
          sm.v.tokens[rr + 1] = (unsigned short)tk;
          tk = sm.v.bpbuf[rr - cch * 32][tk];
        }
        tok = tk;
      }
      __syncthreads();
    }
    if (tid == 0) sm.v.tokens[0] = (unsigned short)tok;
    __syncthreads();
    out_tok[b * Tn + tid] = (float)sm.v.tokens[tid];
  } else if (role <= 3) {
    // ========== PROBE V: viterbi skeleton (no trans/emis loads), x2 steps ==========
    float R = __int_as_float(((const int*)Rp)[0]) * 1.000001f + 1e-4f;
    float vaR = eb[tid];
    sm.v.va2[0][tid] = vaR;
    bar_lgkm();
    float acc = 0.f;
    for (int t = 1; t < Tn * 2; ++t) {
      const int cur = t & 1, prev = cur ^ 1;
      const float* va2p = sm.v.va2[prev];
      const float4* vap4 = (const float4*)va2p;
      float4 q0 = vap4[lane * 2];
      float4 q1 = vap4[lane * 2 + 1];
      float mx8 = fmaxf(fmaxf(fmaxf(q0.x, q0.y), fmaxf(q0.z, q0.w)),
                        fmaxf(fmaxf(q1.x, q1.y), fmaxf(q1.z, q1.w)));
      float gmax = dpp64max(mx8);
      float thr = gmax - R;
      unsigned long long bm[8];
      bm[0] = __ballot(q0.x >= thr);
      bm[1] = __ballot(q0.y >= thr);
      bm[2] = __ballot(q0.z >= thr);
      bm[3] = __ballot(q0.w >= thr);
      bm[4] = __ballot(q1.x >= thr);
      bm[5] = __ballot(q1.y >= thr);
      bm[6] = __ballot(q1.z >= thr);
      bm[7] = __ballot(q1.w >= thr);
      unsigned long long any = bm[0] | bm[1] | bm[2] | bm[3] |
                               bm[4] | bm[5] | bm[6] | bm[7];
      float best = -3e38f; int arg = 0;
      while (any) {
        int l = __ffsll(any) - 1; any &= any - 1;
#pragma unroll
        for (int j = 0; j < 8; ++j) {
          if ((bm[j] >> l) & 1) {
            int u = 8 * l + j;
            float cnd = va2p[u] + 0.0009765625f * (float)u;  // LDS-only candidate
            if (cnd > best) { best = cnd; arg = u; }
          }
        }
      }
      acc += best + (float)arg;
      float nv = va2p[(tid + 1) & 511];   // exact rotation: distribution preserved
      sm.v.va2[cur][tid] = nv;
      vaR = nv;
      bar_lgkm();
    }
    if (acc == 1.2345678e-33f) sink[0] = acc;
  } else {
    // ========== PROBE F: single-barrier forward prototype (stale-m, clamp), x2 steps ==========
    const int g = lane >> 4, c = lane & 15;
    const int t2sel = c >> 2, r2sel = c & 3;
    const int sidx = ((16 * ((lane >> 2) & 3)) + 4 * (lane >> 4) + (lane & 3)) << 2;
    i8v EA[4][4];
    {
      const i8v* E8v = (const i8v*)E8;
#pragma unroll
      for (int vt2 = 0; vt2 < 4; ++vt2)
#pragma unroll
        for (int kc = 0; kc < 4; ++kc)
          EA[vt2][kc] = E8v[((4 * w + vt2) * 4 + kc) * 64 + lane];
    }
    float alphaR = eb[tid];
    float ecur = eb[Vn + tid];
    {
      float r = dpp64max(alphaR);
      if (lane == 0) { sm.f.wred[0][w] = r; sm.f.wred[1][w] = r; }
    }
    bar_lgkm();
    float m_used = max8lds(sm.f.wred[0]);

    for (int t = 1; t < Tn * 2; ++t) {
      const int q = t & 1;
      float p = __expf(fminf(alphaR - m_used, 6.0f));
      sm.f.ph[q][tid] = (unsigned char)f32_to_e4m3(p);
      bar_lgkm();  // SINGLE barrier per step
      float m_next = max8lds(sm.f.wred[q ^ 1]);  // latency hidden under MFMA
      int tt = t & (Tn - 1);
      float enext = eb[(size_t)((tt + 1) & (Tn - 1)) * Vn + tid];
      const uint4* phq = (const uint4*)sm.f.ph[q];
      i8v B4[4];
#pragma unroll
      for (int kc = 0; kc < 4; ++kc) {
        union { uint4 u[2]; i8v v; } bu;
        bu.u[0] = phq[kc * 8 + g * 2];
        bu.u[1] = phq[kc * 8 + g * 2 + 1];
        B4[kc] = bu.v;
      }
      f4 acc0 = (f4)(0.f), acc1 = (f4)(0.f), acc2 = (f4)(0.f), acc3 = (f4)(0.f);
#pragma unroll
      for (int kc = 0; kc < 4; ++kc) {
        acc0 = __builtin_amdgcn_mfma_scale_f32_16x16x128_f8f6f4(
            EA[0][kc], B4[kc], acc0, 0, 0, 0, 0x7F7F7F7F, 0, 0x7F7F7F7F);
        acc1 = __builtin_amdgcn_mfma_scale_f32_16x16x128_f8f6f4(
            EA[1][kc], B4[kc], acc1, 0, 0, 0, 0x7F7F7F7F, 0, 0x7F7F7F7F);
        acc2 = __builtin_amdgcn_mfma_scale_f32_16x16x128_f8f6f4(
            EA[2][kc], B4[kc], acc2, 0, 0, 0, 0x7F7F7F7F, 0, 0x7F7F7F7F);
        acc3 = __builtin_amdgcn_mfma_scale_f32_16x16x128_f8f6f4(
            EA[3][kc], B4[kc], acc3, 0, 0, 0, 0x7F7F7F7F, 0, 0x7F7F7F7F);
      }
      f4 at = (t2sel == 0) ? acc0 : (t2sel == 1) ? acc1 : (t2sel == 2) ? acc2 : acc3;
      float lo = (r2sel & 1) ? at[1] : at[0];
      float hi = (r2sel & 1) ? at[3] : at[2];
      float tot = (r2sel & 2) ? hi : lo;
      float tv = __int_as_float(__builtin_amdgcn_ds_bpermute(sidx, __float_as_int(tot)));
      float nv = m_used + __logf(tv) + ecur;
      alphaR = nv; ecur = enext;
      float rmx = dpp64max(nv);
      if (lane == 0) sm.f.wred[q][w] = rmx;  // visible after next iter's barrier
      m_used = m_next;
    }
    if (alphaR == 1.2345678e-33f) sink[1] = alphaR;
  }
}

extern "C" void kernel_launch(void* const* d_in, const int* in_sizes, int n_in,
                              void* d_out, int out_size, void* d_ws, size_t ws_size,
                              hipStream_t stream) {
  const float* x = (const float*)d_in[0];
  const float* w = (const float*)d_in[1];
  const float* trans = (const float*)d_in[2];
  const int* tgt = (const int*)d_in[3];
  const unsigned char* pad = (const unsigned char*)d_in[4];
  float* out = (float*)d_out;

  char* ws = (char*)d_ws;
  float* Rp = (float*)ws;                                    // 64 B (sink at +32)
  unsigned char* E8 = (unsigned char*)(ws + 64);             // 256 KB fp8 fragments
  unsigned short* bps = (unsigned short*)(ws + 64 + 524288); // ~16.7 MB

  float* emis = out;                 // (B,T,V)
  float* out_ll = out + 8388608;     // (B,)
  float* out_tok = out + 8388640;    // (B,T) as float

  (void)hipMemsetAsync(Rp, 0, 4, stream);
  hipLaunchKernelGGL(crf_minmax, dim3(8), dim3(512), 0, stream, trans, (unsigned int*)Rp);
  hipLaunchKernelGGL(crf_build_E8, dim3(128), dim3(256), 0, stream, trans, E8);
  hipLaunchKernelGGL(crf_gemm, dim3(256), dim3(256), 0, stream, x, w, emis);
  hipLaunchKernelGGL(crf_scan, dim3(192), dim3(512), 0, stream, emis, trans, E8, Rp,
                     tgt, pad, bps, out_ll, out_tok, (float*)(ws + 32));
}

// Round 14
// 772.502 us; speedup vs baseline: 1.6156x; 1.6156x over previous
//
#include <hip/hip_runtime.h>

#define Bn 32
#define Tn 512
#define Dn 512
#define Vn 512

typedef float f4 __attribute__((ext_vector_type(4)));
typedef int i8v __attribute__((ext_vector_type(8)));
typedef _Float16 h8f __attribute__((ext_vector_type(8)));

__device__ __forceinline__ float max8lds(const float* p) {
  float4 a = *(const float4*)p;
  float4 b = *(const float4*)(p + 4);
  return fmaxf(fmaxf(fmaxf(a.x, a.y), fmaxf(a.z, a.w)),
               fmaxf(fmaxf(b.x, b.y), fmaxf(b.z, b.w)));
}

// 64-lane max via DPP (row_shr 1/2/4/8 + bcast15/31), result broadcast via readlane
__device__ __forceinline__ float dpp64max(float x) {
  int t;
  t = __builtin_amdgcn_update_dpp(__float_as_int(x), __float_as_int(x), 0x111, 0xF, 0xF, false);
  x = fmaxf(x, __int_as_float(t));
  t = __builtin_amdgcn_update_dpp(__float_as_int(x), __float_as_int(x), 0x112, 0xF, 0xF, false);
  x = fmaxf(x, __int_as_float(t));
  t = __builtin_amdgcn_update_dpp(__float_as_int(x), __float_as_int(x), 0x114, 0xF, 0xF, false);
  x = fmaxf(x, __int_as_float(t));
  t = __builtin_amdgcn_update_dpp(__float_as_int(x), __float_as_int(x), 0x118, 0xF, 0xF, false);
  x = fmaxf(x, __int_as_float(t));
  t = __builtin_amdgcn_update_dpp(__float_as_int(x), __float_as_int(x), 0x142, 0xF, 0xF, false);
  x = fmaxf(x, __int_as_float(t));
  t = __builtin_amdgcn_update_dpp(__float_as_int(x), __float_as_int(x), 0x143, 0xF, 0xF, false);
  x = fmaxf(x, __int_as_float(t));
  return __int_as_float(__builtin_amdgcn_readlane(__float_as_int(x), 63));
}

// raw barrier: LDS-visibility only (no vmcnt drain -> global ops float across steps)
__device__ __forceinline__ void bar_lgkm() {
  asm volatile("s_waitcnt lgkmcnt(0)" ::: "memory");
  __builtin_amdgcn_s_barrier();
}

// ---- f32 -> OCP e4m3fn, round-to-nearest-even (x >= 0 assumed) ----
__device__ __forceinline__ unsigned int f32_to_e4m3(float x) {
  x = fminf(x, 448.0f);
  unsigned int bits = __float_as_uint(x);
  int e = (int)((bits >> 23) & 0xFF) - 127;
  if (e < -6) {
    return (unsigned int)__float2int_rn(x * 512.0f);
  }
  unsigned int man = bits & 0x7FFFFF;
  int te = e + 7;
  unsigned int r = man >> 20;
  unsigned int rem = man & 0xFFFFF;
  if (rem > 0x80000u || (rem == 0x80000u && (r & 1u))) r++;
  if (r == 8u) { r = 0u; te++; }
  if (te > 15) { te = 15; r = 6u; }
  unsigned int byte = ((unsigned int)te << 3) | r;
  if (byte > 0x7Eu) byte = 0x7Eu;
  return byte;
}

// fast path: HW packed fp8 convert (branch-free); fallback = software RNE
__device__ __forceinline__ unsigned int cvt_e4m3_fast(float p) {
#if __has_builtin(__builtin_amdgcn_cvt_pk_fp8_f32)
  return (unsigned int)(__builtin_amdgcn_cvt_pk_fp8_f32(p, p, 0, false) & 0xFF);
#else
  return f32_to_e4m3(p);
#endif
}

// ---- pruning radius: max over columns v of (max_u T[u][v] - min_u T[u][v]) ----
__global__ __launch_bounds__(512) void crf_minmax(const float* __restrict__ trans,
                                                  unsigned int* __restrict__ Rout) {
  __shared__ float smn[8][64], smx[8][64];
  const int c = threadIdx.x & 63;
  const int seg = threadIdx.x >> 6;
  const int col = (int)blockIdx.x * 64 + c;
  float mn = 3e38f, mx = -3e38f;
#pragma unroll 4
  for (int u = seg * 64; u < seg * 64 + 64; ++u) {
    float t = trans[(size_t)u * Vn + col];
    mn = fminf(mn, t); mx = fmaxf(mx, t);
  }
  smn[seg][c] = mn; smx[seg][c] = mx;
  __syncthreads();
  if (seg == 0) {
#pragma unroll
    for (int i = 1; i < 8; ++i) { mn = fminf(mn, smn[i][c]); mx = fmaxf(mx, smx[i][c]); }
    float r = dpp64max(mx - mn);  // r >= 0
    if (c == 0) atomicMax((int*)Rout, __float_as_int(r));
  }
}

// ---- E8: exp(trans) as fp8 e4m3 MFMA A-fragments for 16x16x128 ----
__global__ __launch_bounds__(256) void crf_build_E8(const float* __restrict__ trans,
                                                    unsigned char* __restrict__ E8) {
  const int fid = (int)blockIdx.x;       // 0..127 = vt*4 + kc
  const int vt = fid >> 2, kc = fid & 3;
  const int t = threadIdx.x;             // 8 bytes per thread
  const int lane = t >> 2;
  const int j0 = (t & 3) * 8;
  const int v = vt * 16 + (lane & 15);
  const int ubase = kc * 128 + (lane >> 4) * 32 + j0;
  unsigned long long pack = 0;
#pragma unroll
  for (int s = 0; s < 8; ++s) {
    float e = __expf(trans[(size_t)(ubase + s) * Vn + v]);
    pack |= (unsigned long long)f32_to_e4m3(e) << (8 * s);
  }
  *(unsigned long long*)(E8 + (size_t)fid * 2048 + lane * 32 + j0) = pack;
}

// ---- emissions via split-f16 MFMA (f32-accurate): BM=64, BN=512, BK=32 ----
__global__ __launch_bounds__(256) void crf_gemm(const float* __restrict__ X,
                                                const float* __restrict__ Wt,
                                                float* __restrict__ C) {
  __shared__ h8f XfH[4][64], XfL[4][64];    // 8 KB
  __shared__ h8f WfH[32][64], WfL[32][64];  // 64 KB
  const int tid = threadIdx.x;
  const int m0 = (int)blockIdx.x * 64;
  const int wv = tid >> 6, lane = tid & 63;
  const int g = lane >> 4, cc = lane & 15;
  const int srow = tid >> 2;                // 0..63
  const int sc0 = (tid & 3) * 8;            // k-chunk 0/8/16/24
  const int p = (tid & 3) * 16 + ((tid >> 2) & 15);  // fragment slot
  f4 acc[32];
#pragma unroll
  for (int i = 0; i < 32; ++i) acc[i] = (f4)(0.f);

  for (int k0 = 0; k0 < Dn; k0 += 32) {
    __syncthreads();
    {
      const float* xp = X + (size_t)(m0 + srow) * Dn + k0 + sc0;
      float4 xa = *(const float4*)xp;
      float4 xb = *(const float4*)(xp + 4);
      float xs[8] = {xa.x, xa.y, xa.z, xa.w, xb.x, xb.y, xb.z, xb.w};
      _Float16 hh[8], ll[8];
#pragma unroll
      for (int i = 0; i < 8; ++i) {
        hh[i] = (_Float16)xs[i];
        ll[i] = (_Float16)(xs[i] - (float)hh[i]);
      }
      XfH[tid >> 6][p] = *(h8f*)hh;
      XfL[tid >> 6][p] = *(h8f*)ll;
#pragma unroll
      for (int i = 0; i < 8; ++i) {
        int r = i * 64 + srow;
        const float* wp = Wt + (size_t)r * Dn + k0 + sc0;
        float4 wa = *(const float4*)wp;
        float4 wb = *(const float4*)(wp + 4);
        float wsv[8] = {wa.x, wa.y, wa.z, wa.w, wb.x, wb.y, wb.z, wb.w};
        _Float16 wh[8], wl[8];
#pragma unroll
        for (int q = 0; q < 8; ++q) {
          wh[q] = (_Float16)wsv[q];
          wl[q] = (_Float16)(wsv[q] - (float)wh[q]);
        }
        WfH[i * 4 + (tid >> 6)][p] = *(h8f*)wh;
        WfL[i * 4 + (tid >> 6)][p] = *(h8f*)wl;
      }
    }
    __syncthreads();
    h8f aH = XfH[wv][lane];
    h8f aL = XfL[wv][lane];
#pragma unroll
    for (int nt = 0; nt < 32; ++nt) {
      h8f bH = WfH[nt][lane];
      h8f bL = WfL[nt][lane];
      acc[nt] = __builtin_amdgcn_mfma_f32_16x16x32_f16(aH, bH, acc[nt], 0, 0, 0);
      acc[nt] = __builtin_amdgcn_mfma_f32_16x16x32_f16(aH, bL, acc[nt], 0, 0, 0);
      acc[nt] = __builtin_amdgcn_mfma_f32_16x16x32_f16(aL, bH, acc[nt], 0, 0, 0);
      acc[nt] = __builtin_amdgcn_mfma_f32_16x16x32_f16(aL, bL, acc[nt], 0, 0, 0);
    }
  }
#pragma unroll
  for (int nt = 0; nt < 32; ++nt)
#pragma unroll
    for (int r = 0; r < 4; ++r)
      C[(size_t)(m0 + wv * 16 + 4 * g + r) * Vn + nt * 16 + cc] = acc[nt][r];
}

// ---- shared-memory union: forward (8-wave) vs viterbi (1-wave) ----
union SM {
  struct {
    __align__(16) unsigned char ph[Vn];   // fp8 p broadcast (512 B)
    __align__(16) float wred[8];
    __align__(16) float wred2[8];
    unsigned char padsh[Tn];
  } f;
  struct {
    __align__(16) float va_lds[64 * 9];          // stride-9 padded mirror of va
    __align__(16) unsigned short bpbuf[16][Vn];  // backtrace chunk
    unsigned short tokens[Tn];
    unsigned char padv[Tn];
  } v1;
};

// ---- fused scan: blocks 0..31 forward (512 thr); 32..63 viterbi (single wave) ----
__global__ __launch_bounds__(512, 2) void crf_scan(
    const float* __restrict__ emis, const float* __restrict__ trans,
    const unsigned char* __restrict__ E8, const float* __restrict__ Rp,
    const int* __restrict__ tgt, const unsigned char* __restrict__ pad,
    unsigned short* __restrict__ bps, float* __restrict__ out_ll,
    float* __restrict__ out_tok) {
  __shared__ SM sm;

  const int tid = threadIdx.x;
  const int b = blockIdx.x & 31;
  const int role = blockIdx.x >> 5;
  const float* eb = emis + (size_t)b * Tn * Vn;
  const int w = tid >> 6;
  const int lane64 = tid & 63;

  if (role == 0) {
    // ========== FORWARD (r12-identical structure; HW fp8 cvt) ==========
    const int g = lane64 >> 4, c = lane64 & 15;
    const int t2sel = c >> 2, r2sel = c & 3;
    const int sidx = ((16 * ((lane64 >> 2) & 3)) + 4 * (lane64 >> 4) + (lane64 & 3)) << 2;
    i8v EA[4][4];
    {
      const i8v* E8v = (const i8v*)E8;
#pragma unroll
      for (int vt2 = 0; vt2 < 4; ++vt2)
#pragma unroll
        for (int kc = 0; kc < 4; ++kc)
          EA[vt2][kc] = E8v[((4 * w + vt2) * 4 + kc) * 64 + lane64];
    }
    sm.f.padsh[tid] = pad[b * Tn + tid];
    float alphaR = eb[tid];
    float ecur = eb[Vn + tid];
    {
      float r = dpp64max(alphaR);
      if (lane64 == 0) sm.f.wred[w] = r;
    }
    bar_lgkm();
    float m = max8lds(sm.f.wred);  // exact max(alpha_{t-1})

    for (int t = 1; t < Tn; ++t) {
      float p = __expf(alphaR - m);            // p in (0, 1]
      sm.f.ph[tid] = (unsigned char)cvt_e4m3_fast(p);
      bar_lgkm();  // A: ph visible
      float enext = (t + 1 < Tn) ? eb[(size_t)(t + 1) * Vn + tid] : 0.f;
      const uint4* phq = (const uint4*)sm.f.ph;
      i8v B4[4];
#pragma unroll
      for (int kc = 0; kc < 4; ++kc) {
        union { uint4 u[2]; i8v v; } bu;
        bu.u[0] = phq[kc * 8 + g * 2];
        bu.u[1] = phq[kc * 8 + g * 2 + 1];
        B4[kc] = bu.v;
      }
      f4 acc0 = (f4)(0.f), acc1 = (f4)(0.f), acc2 = (f4)(0.f), acc3 = (f4)(0.f);
#pragma unroll
      for (int kc = 0; kc < 4; ++kc) {
        acc0 = __builtin_amdgcn_mfma_scale_f32_16x16x128_f8f6f4(
            EA[0][kc], B4[kc], acc0, 0, 0, 0, 0x7F7F7F7F, 0, 0x7F7F7F7F);
        acc1 = __builtin_amdgcn_mfma_scale_f32_16x16x128_f8f6f4(
            EA[1][kc], B4[kc], acc1, 0, 0, 0, 0x7F7F7F7F, 0, 0x7F7F7F7F);
        acc2 = __builtin_amdgcn_mfma_scale_f32_16x16x128_f8f6f4(
            EA[2][kc], B4[kc], acc2, 0, 0, 0, 0x7F7F7F7F, 0, 0x7F7F7F7F);
        acc3 = __builtin_amdgcn_mfma_scale_f32_16x16x128_f8f6f4(
            EA[3][kc], B4[kc], acc3, 0, 0, 0, 0x7F7F7F7F, 0, 0x7F7F7F7F);
      }
      f4 at = (t2sel == 0) ? acc0 : (t2sel == 1) ? acc1 : (t2sel == 2) ? acc2 : acc3;
      float lo = (r2sel & 1) ? at[1] : at[0];
      float hi = (r2sel & 1) ? at[3] : at[2];
      float tot = (r2sel & 2) ? hi : lo;
      float tv = __int_as_float(__builtin_amdgcn_ds_bpermute(sidx, __float_as_int(tot)));
      float nv = m + __logf(tv) + ecur;
      if (sm.f.padsh[t]) nv = alphaR;
      alphaR = nv; ecur = enext;
      float rmx = dpp64max(nv);
      if (lane64 == 0) sm.f.wred[w] = rmx;
      bar_lgkm();  // B: wred visible; ph safe to overwrite next iter
      m = max8lds(sm.f.wred);  // exact max(alpha_t)
    }

    // epilogue: logZ + gold score
    __syncthreads();
    float ex = __expf(alphaR - m);
#pragma unroll
    for (int off = 1; off < 64; off <<= 1) ex += __shfl_xor(ex, off);
    if (lane64 == 0) sm.f.wred[w] = ex;
    float sc;
    {
      int t = tid;
      int tg = tgt[b * Tn + t];
      float mt = sm.f.padsh[t] ? 0.f : 1.f;
      sc = eb[(size_t)t * Vn + tg] * mt;
      if (t < Tn - 1) {
        int tg1 = tgt[b * Tn + t + 1];
        float mt1 = sm.f.padsh[t + 1] ? 0.f : 1.f;
        sc += trans[(size_t)tg * Vn + tg1] * mt * mt1;
      }
    }
#pragma unroll
    for (int off = 1; off < 64; off <<= 1) sc += __shfl_xor(sc, off);
    if (lane64 == 0) sm.f.wred2[w] = sc;
    __syncthreads();
    if (tid == 0) {
      float s = 0.f, gg = 0.f;
      for (int i = 0; i < 8; ++i) { s += sm.f.wred[i]; gg += sm.f.wred2[i]; }
      out_ll[b] = gg - (m + __logf(s));
    }
  } else {
    // ========== VITERBI: single wave, barrier-free (8 states/lane) ==========
    if (tid >= 64) return;  // waves 1..7 retire immediately; NO barriers below
    const int lane = tid;
    float R = __int_as_float(((const int*)Rp)[0]) * 1.000001f + 1e-4f;
#pragma unroll
    for (int i = 0; i < 8; ++i)
      sm.v1.padv[lane * 8 + i] = pad[b * Tn + lane * 8 + i];

    float va[8], ecur[8], enext[8];
    {
      float4 a0 = *(const float4*)(eb + lane * 8);
      float4 a1 = *(const float4*)(eb + lane * 8 + 4);
      va[0] = a0.x; va[1] = a0.y; va[2] = a0.z; va[3] = a0.w;
      va[4] = a1.x; va[5] = a1.y; va[6] = a1.z; va[7] = a1.w;
      float4 e0 = *(const float4*)(eb + Vn + lane * 8);
      float4 e1 = *(const float4*)(eb + Vn + lane * 8 + 4);
      ecur[0] = e0.x; ecur[1] = e0.y; ecur[2] = e0.z; ecur[3] = e0.w;
      ecur[4] = e1.x; ecur[5] = e1.y; ecur[6] = e1.z; ecur[7] = e1.w;
#pragma unroll
      for (int j = 0; j < 8; ++j) enext[j] = 0.f;
    }
#pragma unroll
    for (int j = 0; j < 8; ++j) sm.v1.va_lds[9 * lane + j] = va[j];

    for (int t = 1; t < Tn; ++t) {
      float mx = fmaxf(fmaxf(fmaxf(va[0], va[1]), fmaxf(va[2], va[3])),
                       fmaxf(fmaxf(va[4], va[5]), fmaxf(va[6], va[7])));
      float gmax = dpp64max(mx);
      float thr = gmax - R;
      unsigned long long bm[8];
#pragma unroll
      for (int j = 0; j < 8; ++j) bm[j] = __ballot(va[j] >= thr);
      unsigned long long any = bm[0] | bm[1] | bm[2] | bm[3] |
                               bm[4] | bm[5] | bm[6] | bm[7];
      if (t + 1 < Tn) {
        float4 e0 = *(const float4*)(eb + (size_t)(t + 1) * Vn + lane * 8);
        float4 e1 = *(const float4*)(eb + (size_t)(t + 1) * Vn + lane * 8 + 4);
        enext[0] = e0.x; enext[1] = e0.y; enext[2] = e0.z; enext[3] = e0.w;
        enext[4] = e1.x; enext[5] = e1.y; enext[6] = e1.z; enext[7] = e1.w;
      }
      float best[8]; int arg[8];
#pragma unroll
      for (int j = 0; j < 8; ++j) { best[j] = -3e38f; arg[j] = 0; }
      while (any) {  // ascending l; j ascending -> ascending u (first-index argmax)
        int l = __ffsll(any) - 1; any &= any - 1;
#pragma unroll
        for (int j = 0; j < 8; ++j) {
          if ((bm[j] >> l) & 1) {
            int u = 8 * l + j;
            float vau = sm.v1.va_lds[9 * l + j];
            const float* tr = trans + (size_t)u * Vn + lane * 8;
            float4 t0 = *(const float4*)tr;
            float4 t1 = *(const float4*)(tr + 4);
            float cc0 = vau + t0.x, cc1 = vau + t0.y, cc2 = vau + t0.z, cc3 = vau + t0.w;
            float cc4 = vau + t1.x, cc5 = vau + t1.y, cc6 = vau + t1.z, cc7 = vau + t1.w;
            if (cc0 > best[0]) { best[0] = cc0; arg[0] = u; }
            if (cc1 > best[1]) { best[1] = cc1; arg[1] = u; }
            if (cc2 > best[2]) { best[2] = cc2; arg[2] = u; }
            if (cc3 > best[3]) { best[3] = cc3; arg[3] = u; }
            if (cc4 > best[4]) { best[4] = cc4; arg[4] = u; }
            if (cc5 > best[5]) { best[5] = cc5; arg[5] = u; }
            if (cc6 > best[6]) { best[6] = cc6; arg[6] = u; }
            if (cc7 > best[7]) { best[7] = cc7; arg[7] = u; }
          }
        }
      }
      bool pd = sm.v1.padv[t] != 0;
      __align__(16) unsigned short bp8[8];
#pragma unroll
      for (int j = 0; j < 8; ++j) {
        float nv = best[j] + ecur[j];
        int bp = arg[j];
        if (pd) { nv = va[j]; bp = 8 * lane + j; }
        va[j] = nv;
        bp8[j] = (unsigned short)bp;
        ecur[j] = enext[j];
      }
      *(uint4*)(bps + ((size_t)(t - 1) * Bn + b) * Vn + lane * 8) = *(const uint4*)bp8;
#pragma unroll
      for (int j = 0; j < 8; ++j) sm.v1.va_lds[9 * lane + j] = va[j];
    }

    // drain bps stores (own-wave), then final argmax + backtrace
    asm volatile("s_waitcnt vmcnt(0)" ::: "memory");
    float bv = va[0]; int bi = 8 * lane;
#pragma unroll
    for (int j = 1; j < 8; ++j)
      if (va[j] > bv) { bv = va[j]; bi = 8 * lane + j; }
#pragma unroll
    for (int off = 1; off < 64; off <<= 1) {
      float ov = __shfl_xor(bv, off);
      int oi = __shfl_xor(bi, off);
      if (ov > bv || (ov == bv && oi < bi)) { bv = ov; bi = oi; }
    }
    int tok = bi;  // wave-uniform

    for (int cch = 31; cch >= 0; --cch) {
      int rlo = cch * 16;
      int rhi = rlo + 15; if (rhi > 510) rhi = 510;
#pragma unroll
      for (int rr = 0; rr < 16; ++rr) {
        int row = cch * 16 + rr;
        if (row <= 510) {
          uint4 vdat = *(const uint4*)(bps + ((size_t)row * Bn + b) * Vn + lane * 8);
          *(uint4*)&sm.v1.bpbuf[rr][lane * 8] = vdat;
        }
      }
      asm volatile("s_waitcnt vmcnt(0) lgkmcnt(0)" ::: "memory");
      for (int rr = rhi; rr >= rlo; --rr) {
        if (lane == 0) sm.v1.tokens[rr + 1] = (unsigned short)tok;
        tok = sm.v1.bpbuf[rr - rlo][tok];  // uniform chase
      }
    }
    if (lane == 0) sm.v1.tokens[0] = (unsigned short)tok;
    asm volatile("s_waitcnt lgkmcnt(0)" ::: "memory");
#pragma unroll
    for (int i = 0; i < 8; ++i)
      out_tok[b * Tn + lane * 8 + i] = (float)sm.v1.tokens[lane * 8 + i];
  }
}

extern "C" void kernel_launch(void* const* d_in, const int* in_sizes, int n_in,
                              void* d_out, int out_size, void* d_ws, size_t ws_size,
                              hipStream_t stream) {
  const float* x = (const float*)d_in[0];
  const float* w = (const float*)d_in[1];
  const float* trans = (const float*)d_in[2];
  const int* tgt = (const int*)d_in[3];
  const unsigned char* pad = (const unsigned char*)d_in[4];
  float* out = (float*)d_out;

  char* ws = (char*)d_ws;
  float* Rp = (float*)ws;                                    // 64 B
  unsigned char* E8 = (unsigned char*)(ws + 64);             // 256 KB fp8 fragments
  unsigned short* bps = (unsigned short*)(ws + 64 + 524288); // ~16.7 MB

  float* emis = out;                 // (B,T,V)
  float* out_ll = out + 8388608;     // (B,)
  float* out_tok = out + 8388640;    // (B,T) as float

  (void)hipMemsetAsync(Rp, 0, 4, stream);
  hipLaunchKernelGGL(crf_minmax, dim3(8), dim3(512), 0, stream, trans, (unsigned int*)Rp);
  hipLaunchKernelGGL(crf_build_E8, dim3(128), dim3(256), 0, stream, trans, E8);
  hipLaunchKernelGGL(crf_gemm, dim3(256), dim3(256), 0, stream, x, w, emis);
  hipLaunchKernelGGL(crf_scan, dim3(64), dim3(512), 0, stream, emis, trans, E8, Rp,
                     tgt, pad, bps, out_ll, out_tok);
}

// Round 15
// 585.127 us; speedup vs baseline: 2.1330x; 1.3202x over previous
//
#include <hip/hip_runtime.h>

#define Bn 32
#define Tn 512
#define Dn 512
#define Vn 512

typedef float f4 __attribute__((ext_vector_type(4)));
typedef int i8v __attribute__((ext_vector_type(8)));
typedef _Float16 h8f __attribute__((ext_vector_type(8)));

__device__ __forceinline__ float max8lds(const float* p) {
  float4 a = *(const float4*)p;
  float4 b = *(const float4*)(p + 4);
  return fmaxf(fmaxf(fmaxf(a.x, a.y), fmaxf(a.z, a.w)),
               fmaxf(fmaxf(b.x, b.y), fmaxf(b.z, b.w)));
}

// 64-lane max via DPP (row_shr 1/2/4/8 + bcast15/31), result broadcast via readlane
__device__ __forceinline__ float dpp64max(float x) {
  int t;
  t = __builtin_amdgcn_update_dpp(__float_as_int(x), __float_as_int(x), 0x111, 0xF, 0xF, false);
  x = fmaxf(x, __int_as_float(t));
  t = __builtin_amdgcn_update_dpp(__float_as_int(x), __float_as_int(x), 0x112, 0xF, 0xF, false);
  x = fmaxf(x, __int_as_float(t));
  t = __builtin_amdgcn_update_dpp(__float_as_int(x), __float_as_int(x), 0x114, 0xF, 0xF, false);
  x = fmaxf(x, __int_as_float(t));
  t = __builtin_amdgcn_update_dpp(__float_as_int(x), __float_as_int(x), 0x118, 0xF, 0xF, false);
  x = fmaxf(x, __int_as_float(t));
  t = __builtin_amdgcn_update_dpp(__float_as_int(x), __float_as_int(x), 0x142, 0xF, 0xF, false);
  x = fmaxf(x, __int_as_float(t));
  t = __builtin_amdgcn_update_dpp(__float_as_int(x), __float_as_int(x), 0x143, 0xF, 0xF, false);
  x = fmaxf(x, __int_as_float(t));
  return __int_as_float(__builtin_amdgcn_readlane(__float_as_int(x), 63));
}

// raw barrier: LDS-visibility only (no vmcnt drain -> global ops float across steps)
__device__ __forceinline__ void bar_lgkm() {
  asm volatile("s_waitcnt lgkmcnt(0)" ::: "memory");
  __builtin_amdgcn_s_barrier();
}

// ---- f32 -> OCP e4m3fn, round-to-nearest-even (x >= 0 assumed) ----
__device__ __forceinline__ unsigned int f32_to_e4m3(float x) {
  x = fminf(x, 448.0f);
  unsigned int bits = __float_as_uint(x);
  int e = (int)((bits >> 23) & 0xFF) - 127;
  if (e < -6) {
    return (unsigned int)__float2int_rn(x * 512.0f);
  }
  unsigned int man = bits & 0x7FFFFF;
  int te = e + 7;
  unsigned int r = man >> 20;
  unsigned int rem = man & 0xFFFFF;
  if (rem > 0x80000u || (rem == 0x80000u && (r & 1u))) r++;
  if (r == 8u) { r = 0u; te++; }
  if (te > 15) { te = 15; r = 6u; }
  unsigned int byte = ((unsigned int)te << 3) | r;
  if (byte > 0x7Eu) byte = 0x7Eu;
  return byte;
}

// fast path: HW packed fp8 convert (branch-free); fallback = software RNE
__device__ __forceinline__ unsigned int cvt_e4m3_fast(float p) {
#if __has_builtin(__builtin_amdgcn_cvt_pk_fp8_f32)
  return (unsigned int)(__builtin_amdgcn_cvt_pk_fp8_f32(p, p, 0, false) & 0xFF);
#else
  return f32_to_e4m3(p);
#endif
}

// ---- pruning radius: max over columns v of (max_u T[u][v] - min_u T[u][v]) ----
__global__ __launch_bounds__(512) void crf_minmax(const float* __restrict__ trans,
                                                  unsigned int* __restrict__ Rout) {
  __shared__ float smn[8][64], smx[8][64];
  const int c = threadIdx.x & 63;
  const int seg = threadIdx.x >> 6;
  const int col = (int)blockIdx.x * 64 + c;
  float mn = 3e38f, mx = -3e38f;
#pragma unroll 4
  for (int u = seg * 64; u < seg * 64 + 64; ++u) {
    float t = trans[(size_t)u * Vn + col];
    mn = fminf(mn, t); mx = fmaxf(mx, t);
  }
  smn[seg][c] = mn; smx[seg][c] = mx;
  __syncthreads();
  if (seg == 0) {
#pragma unroll
    for (int i = 1; i < 8; ++i) { mn = fminf(mn, smn[i][c]); mx = fmaxf(mx, smx[i][c]); }
    float r = dpp64max(mx - mn);  // r >= 0
    if (c == 0) atomicMax((int*)Rout, __float_as_int(r));
  }
}

// ---- E8: exp(trans) as fp8 e4m3 MFMA A-fragments for 16x16x128 ----
__global__ __launch_bounds__(256) void crf_build_E8(const float* __restrict__ trans,
                                                    unsigned char* __restrict__ E8) {
  const int fid = (int)blockIdx.x;       // 0..127 = vt*4 + kc
  const int vt = fid >> 2, kc = fid & 3;
  const int t = threadIdx.x;             // 8 bytes per thread
  const int lane = t >> 2;
  const int j0 = (t & 3) * 8;
  const int v = vt * 16 + (lane & 15);
  const int ubase = kc * 128 + (lane >> 4) * 32 + j0;
  unsigned long long pack = 0;
#pragma unroll
  for (int s = 0; s < 8; ++s) {
    float e = __expf(trans[(size_t)(ubase + s) * Vn + v]);
    pack |= (unsigned long long)f32_to_e4m3(e) << (8 * s);
  }
  *(unsigned long long*)(E8 + (size_t)fid * 2048 + lane * 32 + j0) = pack;
}

// ---- emissions via split-f16 MFMA (f32-accurate): BM=64, BN=512, BK=32 ----
__global__ __launch_bounds__(256) void crf_gemm(const float* __restrict__ X,
                                                const float* __restrict__ Wt,
                                                float* __restrict__ C) {
  __shared__ h8f XfH[4][64], XfL[4][64];    // 8 KB
  __shared__ h8f WfH[32][64], WfL[32][64];  // 64 KB
  const int tid = threadIdx.x;
  const int m0 = (int)blockIdx.x * 64;
  const int wv = tid >> 6, lane = tid & 63;
  const int g = lane >> 4, cc = lane & 15;
  const int srow = tid >> 2;                // 0..63
  const int sc0 = (tid & 3) * 8;            // k-chunk 0/8/16/24
  const int p = (tid & 3) * 16 + ((tid >> 2) & 15);  // fragment slot
  f4 acc[32];
#pragma unroll
  for (int i = 0; i < 32; ++i) acc[i] = (f4)(0.f);

  for (int k0 = 0; k0 < Dn; k0 += 32) {
    __syncthreads();
    {
      const float* xp = X + (size_t)(m0 + srow) * Dn + k0 + sc0;
      float4 xa = *(const float4*)xp;
      float4 xb = *(const float4*)(xp + 4);
      float xs[8] = {xa.x, xa.y, xa.z, xa.w, xb.x, xb.y, xb.z, xb.w};
      _Float16 hh[8], ll[8];
#pragma unroll
      for (int i = 0; i < 8; ++i) {
        hh[i] = (_Float16)xs[i];
        ll[i] = (_Float16)(xs[i] - (float)hh[i]);
      }
      XfH[tid >> 6][p] = *(h8f*)hh;
      XfL[tid >> 6][p] = *(h8f*)ll;
#pragma unroll
      for (int i = 0; i < 8; ++i) {
        int r = i * 64 + srow;
        const float* wp = Wt + (size_t)r * Dn + k0 + sc0;
        float4 wa = *(const float4*)wp;
        float4 wb = *(const float4*)(wp + 4);
        float wsv[8] = {wa.x, wa.y, wa.z, wa.w, wb.x, wb.y, wb.z, wb.w};
        _Float16 wh[8], wl[8];
#pragma unroll
        for (int q = 0; q < 8; ++q) {
          wh[q] = (_Float16)wsv[q];
          wl[q] = (_Float16)(wsv[q] - (float)wh[q]);
        }
        WfH[i * 4 + (tid >> 6)][p] = *(h8f*)wh;
        WfL[i * 4 + (tid >> 6)][p] = *(h8f*)wl;
      }
    }
    __syncthreads();
    h8f aH = XfH[wv][lane];
    h8f aL = XfL[wv][lane];
#pragma unroll
    for (int nt = 0; nt < 32; ++nt) {
      h8f bH = WfH[nt][lane];
      h8f bL = WfL[nt][lane];
      acc[nt] = __builtin_amdgcn_mfma_f32_16x16x32_f16(aH, bH, acc[nt], 0, 0, 0);
      acc[nt] = __builtin_amdgcn_mfma_f32_16x16x32_f16(aH, bL, acc[nt], 0, 0, 0);
      acc[nt] = __builtin_amdgcn_mfma_f32_16x16x32_f16(aL, bH, acc[nt], 0, 0, 0);
      acc[nt] = __builtin_amdgcn_mfma_f32_16x16x32_f16(aL, bL, acc[nt], 0, 0, 0);
    }
  }
#pragma unroll
  for (int nt = 0; nt < 32; ++nt)
#pragma unroll
    for (int r = 0; r < 4; ++r)
      C[(size_t)(m0 + wv * 16 + 4 * g + r) * Vn + nt * 16 + cc] = acc[nt][r];
}

// ---- shared-memory union: forward vs viterbi roles ----
union SM {
  struct {
    __align__(16) unsigned char ph[Vn];   // fp8 p broadcast (512 B)
    __align__(16) float wred[8];
    __align__(16) float wred2[8];
    unsigned char padsh[Tn];
  } f;
  struct {
    __align__(16) float va2[2][Vn];
    __align__(16) unsigned short bpbuf[32][Vn];
    unsigned short tokens[Tn];
    __align__(16) float wvals[8];
    int widxs[8];
    unsigned char padsh[Tn];
    int lastS;
  } v;
};

// ---- fused scan: blocks 0..31 forward(logZ,loglik); 32..63 viterbi+backtrace ----
__global__ __launch_bounds__(512, 2) void crf_scan(
    const float* __restrict__ emis, const float* __restrict__ trans,
    const unsigned char* __restrict__ E8, const float* __restrict__ Rp,
    const int* __restrict__ tgt, const unsigned char* __restrict__ pad,
    unsigned short* __restrict__ bps, float* __restrict__ out_ll,
    float* __restrict__ out_tok) {
  __shared__ SM sm;

  const int tid = threadIdx.x;
  const int b = blockIdx.x & 31;
  const int role = blockIdx.x >> 5;
  const float* eb = emis + (size_t)b * Tn * Vn;
  const int w = tid >> 6;
  const int lane = tid & 63;

  if (role == 0) {
    // ========== FORWARD (MX-FP8 MFMA K=128, exact-m, 2-deep MFMA chains) ==========
    const int g = lane >> 4, c = lane & 15;
    const int t2sel = c >> 2, r2sel = c & 3;
    const int sidx = ((16 * ((lane >> 2) & 3)) + 4 * (lane >> 4) + (lane & 3)) << 2;
    i8v EA[4][4];
    {
      const i8v* E8v = (const i8v*)E8;
#pragma unroll
      for (int vt2 = 0; vt2 < 4; ++vt2)
#pragma unroll
        for (int kc = 0; kc < 4; ++kc)
          EA[vt2][kc] = E8v[((4 * w + vt2) * 4 + kc) * 64 + lane];
    }
    sm.f.padsh[tid] = pad[b * Tn + tid];
    float alphaR = eb[tid];
    float ecur = eb[Vn + tid];
    {
      float r = dpp64max(alphaR);
      if (lane == 0) sm.f.wred[w] = r;
    }
    bar_lgkm();
    float m = max8lds(sm.f.wred);  // exact max(alpha_{t-1})

    const f4 z4 = (f4)(0.f);
    for (int t = 1; t < Tn; ++t) {
      float p = __expf(alphaR - m);            // p in (0, 1]
      sm.f.ph[tid] = (unsigned char)cvt_e4m3_fast(p);
      bar_lgkm();  // A: ph visible
      float enext = (t + 1 < Tn) ? eb[(size_t)(t + 1) * Vn + tid] : 0.f;
      const uint4* phq = (const uint4*)sm.f.ph;
      i8v B4[4];
#pragma unroll
      for (int kc = 0; kc < 4; ++kc) {
        union { uint4 u[2]; i8v v; } bu;
        bu.u[0] = phq[kc * 8 + g * 2];
        bu.u[1] = phq[kc * 8 + g * 2 + 1];
        B4[kc] = bu.v;
      }
      // 8 accumulators, 2-deep chains (kc{0,1} -> A, kc{2,3} -> B), C=z4 init
      f4 aA0 = __builtin_amdgcn_mfma_scale_f32_16x16x128_f8f6f4(
          EA[0][0], B4[0], z4, 0, 0, 0, 0x7F7F7F7F, 0, 0x7F7F7F7F);
      f4 aB0 = __builtin_amdgcn_mfma_scale_f32_16x16x128_f8f6f4(
          EA[0][2], B4[2], z4, 0, 0, 0, 0x7F7F7F7F, 0, 0x7F7F7F7F);
      f4 aA1 = __builtin_amdgcn_mfma_scale_f32_16x16x128_f8f6f4(
          EA[1][0], B4[0], z4, 0, 0, 0, 0x7F7F7F7F, 0, 0x7F7F7F7F);
      f4 aB1 = __builtin_amdgcn_mfma_scale_f32_16x16x128_f8f6f4(
          EA[1][2], B4[2], z4, 0, 0, 0, 0x7F7F7F7F, 0, 0x7F7F7F7F);
      f4 aA2 = __builtin_amdgcn_mfma_scale_f32_16x16x128_f8f6f4(
          EA[2][0], B4[0], z4, 0, 0, 0, 0x7F7F7F7F, 0, 0x7F7F7F7F);
      f4 aB2 = __builtin_amdgcn_mfma_scale_f32_16x16x128_f8f6f4(
          EA[2][2], B4[2], z4, 0, 0, 0, 0x7F7F7F7F, 0, 0x7F7F7F7F);
      f4 aA3 = __builtin_amdgcn_mfma_scale_f32_16x16x128_f8f6f4(
          EA[3][0], B4[0], z4, 0, 0, 0, 0x7F7F7F7F, 0, 0x7F7F7F7F);
      f4 aB3 = __builtin_amdgcn_mfma_scale_f32_16x16x128_f8f6f4(
          EA[3][2], B4[2], z4, 0, 0, 0, 0x7F7F7F7F, 0, 0x7F7F7F7F);
      aA0 = __builtin_amdgcn_mfma_scale_f32_16x16x128_f8f6f4(
          EA[0][1], B4[1], aA0, 0, 0, 0, 0x7F7F7F7F, 0, 0x7F7F7F7F);
      aB0 = __builtin_amdgcn_mfma_scale_f32_16x16x128_f8f6f4(
          EA[0][3], B4[3], aB0, 0, 0, 0, 0x7F7F7F7F, 0, 0x7F7F7F7F);
      aA1 = __builtin_amdgcn_mfma_scale_f32_16x16x128_f8f6f4(
          EA[1][1], B4[1], aA1, 0, 0, 0, 0x7F7F7F7F, 0, 0x7F7F7F7F);
      aB1 = __builtin_amdgcn_mfma_scale_f32_16x16x128_f8f6f4(
          EA[1][3], B4[3], aB1, 0, 0, 0, 0x7F7F7F7F, 0, 0x7F7F7F7F);
      aA2 = __builtin_amdgcn_mfma_scale_f32_16x16x128_f8f6f4(
          EA[2][1], B4[1], aA2, 0, 0, 0, 0x7F7F7F7F, 0, 0x7F7F7F7F);
      aB2 = __builtin_amdgcn_mfma_scale_f32_16x16x128_f8f6f4(
          EA[2][3], B4[3], aB2, 0, 0, 0, 0x7F7F7F7F, 0, 0x7F7F7F7F);
      aA3 = __builtin_amdgcn_mfma_scale_f32_16x16x128_f8f6f4(
          EA[3][1], B4[1], aA3, 0, 0, 0, 0x7F7F7F7F, 0, 0x7F7F7F7F);
      aB3 = __builtin_amdgcn_mfma_scale_f32_16x16x128_f8f6f4(
          EA[3][3], B4[3], aB3, 0, 0, 0, 0x7F7F7F7F, 0, 0x7F7F7F7F);
      f4 s0 = aA0 + aB0;
      f4 s1 = aA1 + aB1;
      f4 s2 = aA2 + aB2;
      f4 s3 = aA3 + aB3;
      // lane (g,c) holds D[4g+r][c] of tile t2sel; one intra-wave bpermute redistributes
      f4 at = (t2sel == 0) ? s0 : (t2sel == 1) ? s1 : (t2sel == 2) ? s2 : s3;
      float lo = (r2sel & 1) ? at[1] : at[0];
      float hi = (r2sel & 1) ? at[3] : at[2];
      float tot = (r2sel & 2) ? hi : lo;
      float tv = __int_as_float(__builtin_amdgcn_ds_bpermute(sidx, __float_as_int(tot)));
      float nv = m + __logf(tv) + ecur;
      if (sm.f.padsh[t]) nv = alphaR;
      alphaR = nv; ecur = enext;
      float rmx = dpp64max(nv);
      if (lane == 0) sm.f.wred[w] = rmx;
      bar_lgkm();  // B: wred visible; ph safe to overwrite next iter
      m = max8lds(sm.f.wred);  // exact max(alpha_t)
    }

    // epilogue: logZ + gold score (m = exact max alpha_511)
    __syncthreads();
    float ex = __expf(alphaR - m);
#pragma unroll
    for (int off = 1; off < 64; off <<= 1) ex += __shfl_xor(ex, off);
    if (lane == 0) sm.f.wred[w] = ex;
    float sc;
    {
      int t = tid;
      int tg = tgt[b * Tn + t];
      float mt = sm.f.padsh[t] ? 0.f : 1.f;
      sc = eb[(size_t)t * Vn + tg] * mt;
      if (t < Tn - 1) {
        int tg1 = tgt[b * Tn + t + 1];
        float mt1 = sm.f.padsh[t + 1] ? 0.f : 1.f;
        sc += trans[(size_t)tg * Vn + tg1] * mt * mt1;
      }
    }
#pragma unroll
    for (int off = 1; off < 64; off <<= 1) sc += __shfl_xor(sc, off);
    if (lane == 0) sm.f.wred2[w] = sc;
    __syncthreads();
    if (tid == 0) {
      float s = 0.f, gg = 0.f;
      for (int i = 0; i < 8; ++i) { s += sm.f.wred[i]; gg += sm.f.wred2[i]; }
      out_ll[b] = gg - (m + __logf(s));
    }
  } else {
    // ========== VITERBI (8-wave, 1 barrier/step, conflict-free wave-order masks) ==========
    float R = __int_as_float(((const int*)Rp)[0]) * 1.000001f + 1e-4f;
    sm.v.padsh[tid] = pad[b * Tn + tid];
    float vaR = eb[tid];
    sm.v.va2[0][tid] = vaR;
    float ecur = eb[Vn + tid];
    bar_lgkm();

    for (int t = 1; t < Tn; ++t) {
      const int cur = t & 1, prev = cur ^ 1;
      const float* va2p = sm.v.va2[prev];
      float enext = (t + 1 < Tn) ? eb[(size_t)(t + 1) * Vn + tid] : 0.f;  // L3 load first
      // column-order reads: qv[j] = va[64j + lane] (conflict-free), masks in wave order
      float qv[8];
#pragma unroll
      for (int j = 0; j < 8; ++j) qv[j] = va2p[64 * j + lane];
      float mx8 = fmaxf(fmaxf(fmaxf(qv[0], qv[1]), fmaxf(qv[2], qv[3])),
                        fmaxf(fmaxf(qv[4], qv[5]), fmaxf(qv[6], qv[7])));
      float gmax = dpp64max(mx8);
      float thr = gmax - R;
      unsigned long long bm[8];
#pragma unroll
      for (int j = 0; j < 8; ++j) bm[j] = __ballot(qv[j] >= thr);
      float best = -3e38f; int arg = 0;
#pragma unroll
      for (int j = 0; j < 8; ++j) {  // j outer, bit l inner: u = 64j + l ascending
        unsigned long long mask = bm[j];
        while (mask) {
          int l = __ffsll(mask) - 1; mask &= mask - 1;
          int u = 64 * j + l;
          float cnd = va2p[u] + trans[(size_t)u * Vn + tid];
          if (cnd > best) { best = cnd; arg = u; }
        }
      }
      float nv = best + ecur; int bp = arg;
      if (sm.v.padsh[t]) { nv = vaR; bp = tid; }
      bps[((size_t)(t - 1) * Bn + b) * Vn + tid] = (unsigned short)bp;  // floats free
      sm.v.va2[cur][tid] = nv;
      vaR = nv; ecur = enext;
      bar_lgkm();  // single barrier: va2[cur] visible
    }

    // drain bps stores once, then backtrace
    asm volatile("s_waitcnt vmcnt(0)" ::: "memory");
    __syncthreads();

    {
      float val = vaR;
      int idx = tid;
#pragma unroll
      for (int off = 1; off < 64; off <<= 1) {
        float ov = __shfl_xor(val, off);
        int oi = __shfl_xor(idx, off);
        if (ov > val || (ov == val && oi < idx)) { val = ov; idx = oi; }
      }
      if (lane == 0) { sm.v.wvals[w] = val; sm.v.widxs[w] = idx; }
    }
    __syncthreads();
    if (tid == 0) {
      float bv = sm.v.wvals[0]; int bi = sm.v.widxs[0];
      for (int i = 1; i < 8; ++i)
        if (sm.v.wvals[i] > bv || (sm.v.wvals[i] == bv && sm.v.widxs[i] < bi)) {
          bv = sm.v.wvals[i]; bi = sm.v.widxs[i];
        }
      sm.v.lastS = bi;
    }
    __syncthreads();
    int tok = sm.v.lastS;

    // backtrace: rows 510..0, 32-row LDS chunks
    for (int cch = 15; cch >= 0; --cch) {
      int rhi = cch * 32 + 31; if (rhi > 510) rhi = 510;
      int srow = tid >> 4, part = tid & 15;
      int row = cch * 32 + srow;
      if (row <= 510) {
        const uint4* src = (const uint4*)(bps + ((size_t)row * Bn + b) * Vn);
        uint4* dst = (uint4*)&sm.v.bpbuf[srow][0];
#pragma unroll
        for (int qq = 0; qq < 4; ++qq) dst[part * 4 + qq] = src[part * 4 + qq];
      }
      __syncthreads();
      if (tid == 0) {
        int tk = tok;
        for (int rr = rhi; rr >= cch * 32; --rr) {
          sm.v.tokens[rr + 1] = (unsigned short)tk;
          tk = sm.v.bpbuf[rr - cch * 32][tk];
        }
        tok = tk;
      }
      __syncthreads();
    }
    if (tid == 0) sm.v.tokens[0] = (unsigned short)tok;
    __syncthreads();
    out_tok[b * Tn + tid] = (float)sm.v.tokens[tid];
  }
}

extern "C" void kernel_launch(void* const* d_in, const int* in_sizes, int n_in,
                              void* d_out, int out_size, void* d_ws, size_t ws_size,
                              hipStream_t stream) {
  const float* x = (const float*)d_in[0];
  const float* w = (const float*)d_in[1];
  const float* trans = (const float*)d_in[2];
  const int* tgt = (const int*)d_in[3];
  const unsigned char* pad = (const unsigned char*)d_in[4];
  float* out = (float*)d_out;

  char* ws = (char*)d_ws;
  float* Rp = (float*)ws;                                    // 64 B
  unsigned char* E8 = (unsigned char*)(ws + 64);             // 256 KB fp8 fragments
  unsigned short* bps = (unsigned short*)(ws + 64 + 524288); // ~16.7 MB

  float* emis = out;                 // (B,T,V)
  float* out_ll = out + 8388608;     // (B,)
  float* out_tok = out + 8388640;    // (B,T) as float

  (void)hipMemsetAsync(Rp, 0, 4, stream);
  hipLaunchKernelGGL(crf_minmax, dim3(8), dim3(512), 0, stream, trans, (unsigned int*)Rp);
  hipLaunchKernelGGL(crf_build_E8, dim3(128), dim3(256), 0, stream, trans, E8);
  hipLaunchKernelGGL(crf_gemm, dim3(256), dim3(256), 0, stream, x, w, emis);
  hipLaunchKernelGGL(crf_scan, dim3(64), dim3(512), 0, stream, emis, trans, E8, Rp,
                     tgt, pad, bps, out_ll, out_tok);
}